// Round 5
// baseline (211.197 us; speedup 1.0000x reference)
//
#include <hip/hip_runtime.h>

#define H 8
#define DH 64
#define NQ 1024
#define NK 2048
#define DIN 512
#define B 4
#define KSPLIT 2
#define KRANGE (NK / KSPLIT)   // 1024
#define KTILES (KRANGE / 64)   // 16
#define BHNQ (B * H * NQ)

typedef __bf16 bf16;
typedef __bf16 bf16x8 __attribute__((ext_vector_type(8)));
typedef __bf16 bf16x4 __attribute__((ext_vector_type(4)));
typedef float floatx4 __attribute__((ext_vector_type(4)));

__device__ inline void gload16(const void* g, void* l) {
  __builtin_amdgcn_global_load_lds(
      (const __attribute__((address_space(1))) void*)g,
      (__attribute__((address_space(3))) void*)l, 16, 0, 0);
}

// ---------------- fp32 -> bf16 convert, all six tensors in one launch --------
__global__ void cvt_all(const float* __restrict__ x, const float* __restrict__ ctx,
                        const float* __restrict__ wq, const float* __restrict__ wk,
                        const float* __restrict__ wv, const float* __restrict__ wo,
                        bf16* xb, bf16* cb, bf16* wqb, bf16* wkb, bf16* wvb, bf16* wob) {
  long i = ((long)blockIdx.x * 256 + threadIdx.x) * 4;
  const float* s; bf16* d; long o;
  if (i < 2097152)      { s = x;   d = xb;  o = i; }
  else if (i < 6291456) { s = ctx; d = cb;  o = i - 2097152; }
  else if (i < 6553600) { s = wq;  d = wqb; o = i - 6291456; }
  else if (i < 6815744) { s = wk;  d = wkb; o = i - 6553600; }
  else if (i < 7077888) { s = wv;  d = wvb; o = i - 6815744; }
  else                  { s = wo;  d = wob; o = i - 7077888; }
  float4 f = *(const float4*)(s + o);
  bf16x4 v = { (bf16)f.x, (bf16)f.y, (bf16)f.z, (bf16)f.w };
  *(bf16x4*)(d + o) = v;
}

// ---------------- fused Q/K/V projection GEMM (C = A @ W^T) ------------------
__global__ __launch_bounds__(256) void gemm_qkv(
    const bf16* __restrict__ xb, const bf16* __restrict__ cb,
    const bf16* __restrict__ wqb, const bf16* __restrict__ wkb, const bf16* __restrict__ wvb,
    bf16* __restrict__ qb, bf16* __restrict__ kb, bf16* __restrict__ vtb) {
  const int which = blockIdx.z;
  if (which == 0 && blockIdx.y >= 32) return;
  const bf16* A = (which == 0) ? xb : cb;
  const bf16* W = (which == 0) ? wqb : ((which == 1) ? wkb : wvb);
  bf16* outb = (which == 0) ? qb : ((which == 1) ? kb : vtb);
  const int logT = (which == 0) ? 10 : 11;
  const float scale = (which == 0) ? 0.125f : 1.0f;
  const bool vmode = (which == 2);

  __shared__ bf16 Al[2][128 * 32];
  __shared__ bf16 Bl[2][128 * 32];
  const int t = threadIdx.x;
  const int lane = t & 63, w = t >> 6;
  const int ln = lane & 15, quad = lane >> 4;
  const int wm = (w >> 1) * 64, wn = (w & 1) * 64;
  const int rowBase = blockIdx.y * 128;
  const int colBase = blockIdx.x * 128;

  floatx4 acc[4][4] = {};
  const int c0 = t, c1 = t + 256;
  const int r0 = c0 >> 2, o0 = (c0 & 3) * 8;
  const int r1 = c1 >> 2, o1 = (c1 & 3) * 8;
  const bf16* Ab = A + (size_t)rowBase * DIN;
  const bf16* Wb = W + (size_t)colBase * DIN;

  gload16(Ab + (size_t)r0 * DIN + o0, &Al[0][c0 * 8]);
  gload16(Ab + (size_t)r1 * DIN + o1, &Al[0][c1 * 8]);
  gload16(Wb + (size_t)r0 * DIN + o0, &Bl[0][c0 * 8]);
  gload16(Wb + (size_t)r1 * DIN + o1, &Bl[0][c1 * 8]);
  __syncthreads();

  for (int k0 = 0; k0 < DIN; k0 += 32) {
    const int cur = (k0 >> 5) & 1, nxt = cur ^ 1;
    if (k0 + 32 < DIN) {
      gload16(Ab + (size_t)r0 * DIN + k0 + 32 + o0, &Al[nxt][c0 * 8]);
      gload16(Ab + (size_t)r1 * DIN + k0 + 32 + o1, &Al[nxt][c1 * 8]);
      gload16(Wb + (size_t)r0 * DIN + k0 + 32 + o0, &Bl[nxt][c0 * 8]);
      gload16(Wb + (size_t)r1 * DIN + k0 + 32 + o1, &Bl[nxt][c1 * 8]);
    }
    bf16x8 af[4], bfr[4];
#pragma unroll
    for (int i = 0; i < 4; i++)
      af[i] = *(const bf16x8*)&Al[cur][(wm + i * 16 + ln) * 32 + quad * 8];
#pragma unroll
    for (int j = 0; j < 4; j++)
      bfr[j] = *(const bf16x8*)&Bl[cur][(wn + j * 16 + ln) * 32 + quad * 8];
#pragma unroll
    for (int i = 0; i < 4; i++)
#pragma unroll
      for (int j = 0; j < 4; j++)
        acc[i][j] = __builtin_amdgcn_mfma_f32_16x16x32_bf16(af[i], bfr[j], acc[i][j], 0, 0, 0);
    __syncthreads();
  }

  const int T = 1 << logT;
#pragma unroll
  for (int i = 0; i < 4; i++)
#pragma unroll
    for (int j = 0; j < 4; j++)
#pragma unroll
      for (int r = 0; r < 4; r++) {
        const int m = rowBase + wm + i * 16 + quad * 4 + r;
        const int n = colBase + wn + j * 16 + ln;
        const float v = acc[i][j][r] * scale;
        const int bb = m >> logT, tok = m & (T - 1);
        const int hh = n >> 6, d = n & 63;
        if (!vmode)
          outb[((((size_t)(bb * H + hh)) << logT) + tok) * DH + d] = (bf16)v;
        else
          outb[(((size_t)(bb * H + hh) * DH + d) << logT) + tok] = (bf16)v;
      }
}

// ---------------- flash attention, static-max softmax, Nk-split --------------
// grid (NQ/32, H, B*KSPLIT), block 128 (2 waves; wave w owns q-rows q0+w*16..+15).
// Single-buffer K/V (20 KB LDS -> high residency); XOR source-permute swizzle;
// bias loaded per tile into registers as the QK^T accumulator init;
// l accumulated via an extra MFMA against an all-ones B fragment.
__global__ __launch_bounds__(128) void attn_fwd(
    const bf16* __restrict__ q, const bf16* __restrict__ k,
    const bf16* __restrict__ vt, const float* __restrict__ bias,
    float* __restrict__ op0, float* __restrict__ op1, float* __restrict__ lpart) {
  __shared__ bf16 KL[64 * 64];     // 8 KB
  __shared__ bf16 VL[64 * 64];     // 8 KB
  __shared__ bf16 Pl[2][16 * 64];  // 4 KB
  const int tid = threadIdx.x;
  const int lane = tid & 63, w = tid >> 6;
  const int ln = lane & 15, quad = lane >> 4;
  const int hh = blockIdx.y;
  const int b = blockIdx.z >> 1, ks = blockIdx.z & 1;
  const int q0 = blockIdx.x * 32;
  const int k0 = ks * KRANGE;
  const size_t bh = (size_t)b * H + hh;
  const bf16* qp = q + bh * NQ * DH;
  const bf16* kp = k + bh * NK * DH;
  const bf16* vp = vt + bh * DH * NK;
  const float* bp = bias + ((size_t)b * NQ + q0 + w * 16 + quad * 4) * NK + ln;
  bf16* pl = &Pl[w][0];

  bf16x8 qf[2];
#pragma unroll
  for (int kc = 0; kc < 2; kc++)
    qf[kc] = *(const bf16x8*)(qp + (size_t)(q0 + w * 16 + ln) * DH + kc * 32 + quad * 8);

  floatx4 o[4] = {};
  floatx4 lac = {};
  const bf16x8 ones = {(bf16)1.f, (bf16)1.f, (bf16)1.f, (bf16)1.f,
                       (bf16)1.f, (bf16)1.f, (bf16)1.f, (bf16)1.f};
  constexpr float L2E = 1.44269504f;
  constexpr float OFF = 34.6246810f;  // 24 * log2(e); scores+bias << 24 always

  for (int tt = 0; tt < KTILES; tt++) {
    const int nk0 = k0 + tt * 64;
    // ---- stage K,V (8 KB each) via DMA; bias tile into registers ----
#pragma unroll
    for (int s = 0; s < 4; s++) {
      const int i = s * 128 + tid;
      const int sr = i >> 3, sc = (i & 7) ^ (sr & 7);
      gload16(kp + (size_t)(nk0 + sr) * DH + sc * 8, &KL[i * 8]);
      gload16(vp + (size_t)sr * NK + nk0 + sc * 8, &VL[i * 8]);
    }
    float bc[4][4];
#pragma unroll
    for (int j = 0; j < 4; j++)
#pragma unroll
      for (int r = 0; r < 4; r++)
        bc[j][r] = bp[(size_t)r * NK + nk0 + j * 16];
    __syncthreads();  // drains DMA + bias loads, publishes KL/VL

    // ---- QK^T with accumulator initialized to the bias tile ----
    floatx4 s4[4];
#pragma unroll
    for (int j = 0; j < 4; j++) {
      s4[j][0] = bc[j][0]; s4[j][1] = bc[j][1];
      s4[j][2] = bc[j][2]; s4[j][3] = bc[j][3];
    }
#pragma unroll
    for (int j = 0; j < 4; j++)
#pragma unroll
      for (int kc = 0; kc < 2; kc++) {
        const int kr = j * 16 + ln;
        bf16x8 kf = *(const bf16x8*)&KL[kr * 64 + (((kc * 4 + quad) ^ (kr & 7)) * 8)];
        s4[j] = __builtin_amdgcn_mfma_f32_16x16x32_bf16(qf[kc], kf, s4[j], 0, 0, 0);
      }

    // ---- p = exp2(s*L2E - OFF) ----
#pragma unroll
    for (int j = 0; j < 4; j++)
#pragma unroll
      for (int r = 0; r < 4; r++)
        s4[j][r] = exp2f(fmaf(s4[j][r], L2E, -OFF));

    // ---- P: C-layout -> per-wave swizzled LDS -> A-layout fragments ----
#pragma unroll
    for (int j = 0; j < 4; j++)
#pragma unroll
      for (int r = 0; r < 4; r++) {
        const int m = quad * 4 + r;
        pl[m * 64 + (((j * 2 + (ln >> 3)) ^ (m & 7)) * 8) + (ln & 7)] = (bf16)s4[j][r];
      }
    asm volatile("s_waitcnt lgkmcnt(0)" ::: "memory");
    bf16x8 pf[2];
#pragma unroll
    for (int kc = 0; kc < 2; kc++)
      pf[kc] = *(const bf16x8*)&pl[ln * 64 + (((kc * 4 + quad) ^ (ln & 7)) * 8)];

    // ---- l += P @ ones (row-sum in every lane) ----
#pragma unroll
    for (int kc = 0; kc < 2; kc++)
      lac = __builtin_amdgcn_mfma_f32_16x16x32_bf16(pf[kc], ones, lac, 0, 0, 0);

    // ---- O += P @ V ----
#pragma unroll
    for (int jn = 0; jn < 4; jn++)
#pragma unroll
      for (int kc = 0; kc < 2; kc++) {
        const int vr = jn * 16 + ln;
        bf16x8 vf = *(const bf16x8*)&VL[vr * 64 + (((kc * 4 + quad) ^ (vr & 7)) * 8)];
        o[jn] = __builtin_amdgcn_mfma_f32_16x16x32_bf16(pf[kc], vf, o[jn], 0, 0, 0);
      }
    __syncthreads();  // protect KL/VL before next stage
  }

  float* op = (ks ? op1 : op0) +
              ((size_t)b * NQ + q0 + w * 16 + quad * 4) * DIN + hh * 64 + ln;
#pragma unroll
  for (int jn = 0; jn < 4; jn++)
#pragma unroll
    for (int r = 0; r < 4; r++)
      op[(size_t)r * DIN + jn * 16] = o[jn][r];

  if (ln == 0) {
    float4 lv = {lac[0], lac[1], lac[2], lac[3]};
    *(float4*)&lpart[((size_t)ks * B * H + b * H + hh) * NQ + q0 + w * 16 + quad * 4] = lv;
  }
}

// ---------------- final projection fused with K-split combine ----------------
// out = ((op0+op1) * (1/l)) @ Wo^T + bo. A staged through VGPRs (load fp32
// partials, combine+normalize, cvt bf16, ds_write); B staged via DMA.
__global__ __launch_bounds__(256) void gemm_out(
    const float* __restrict__ op0, const float* __restrict__ op1,
    const float* __restrict__ lp, const bf16* __restrict__ W,
    float* __restrict__ outf, const float* __restrict__ bo) {
  __shared__ bf16 Al[2][128 * 32];
  __shared__ bf16 Bl[2][128 * 32];
  const int t = threadIdx.x;
  const int lane = t & 63, w = t >> 6;
  const int ln = lane & 15, quad = lane >> 4;
  const int wm = (w >> 1) * 64, wn = (w & 1) * 64;
  const int rowBase = blockIdx.y * 128;
  const int colBase = blockIdx.x * 128;

  floatx4 acc[4][4] = {};
  const int c0 = t, c1 = t + 256;
  const int r0 = c0 >> 2, o0 = (c0 & 3) * 8;
  const int r1 = c1 >> 2, o1 = (c1 & 3) * 8;
  const int m0 = rowBase + r0, m1 = rowBase + r1;
  const bf16* Wb = W + (size_t)colBase * DIN;

  // per-head 1/l for both staged rows (k-loop unrolled -> constant indexing)
  float linv0[8], linv1[8];
#pragma unroll
  for (int h = 0; h < 8; h++) {
    const int i0 = ((m0 >> 10) * H + h) * NQ + (m0 & 1023);
    const int i1 = ((m1 >> 10) * H + h) * NQ + (m1 & 1023);
    linv0[h] = 1.0f / (lp[i0] + lp[BHNQ + i0]);
    linv1[h] = 1.0f / (lp[i1] + lp[BHNQ + i1]);
  }

#define STAGE_A(K0V, BUF)                                                      \
  {                                                                            \
    const float sA = linv0[(K0V) >> 6], sB = linv1[(K0V) >> 6];                \
    const float* pa0 = op0 + (size_t)m0 * DIN + (K0V) + o0;                    \
    const float* pa1 = op1 + (size_t)m0 * DIN + (K0V) + o0;                    \
    const float* pb0 = op0 + (size_t)m1 * DIN + (K0V) + o1;                    \
    const float* pb1 = op1 + (size_t)m1 * DIN + (K0V) + o1;                    \
    float4 xa = *(const float4*)pa0, xb2 = *(const float4*)(pa0 + 4);          \
    float4 ya = *(const float4*)pa1, yb = *(const float4*)(pa1 + 4);           \
    float4 za = *(const float4*)pb0, zb = *(const float4*)(pb0 + 4);           \
    float4 ua = *(const float4*)pb1, ub = *(const float4*)(pb1 + 4);           \
    bf16x8 v0 = {(bf16)((xa.x + ya.x) * sA), (bf16)((xa.y + ya.y) * sA),       \
                 (bf16)((xa.z + ya.z) * sA), (bf16)((xa.w + ya.w) * sA),       \
                 (bf16)((xb2.x + yb.x) * sA), (bf16)((xb2.y + yb.y) * sA),     \
                 (bf16)((xb2.z + yb.z) * sA), (bf16)((xb2.w + yb.w) * sA)};    \
    bf16x8 v1 = {(bf16)((za.x + ua.x) * sB), (bf16)((za.y + ua.y) * sB),       \
                 (bf16)((za.z + ua.z) * sB), (bf16)((za.w + ua.w) * sB),       \
                 (bf16)((zb.x + ub.x) * sB), (bf16)((zb.y + ub.y) * sB),       \
                 (bf16)((zb.z + ub.z) * sB), (bf16)((zb.w + ub.w) * sB)};      \
    *(bf16x8*)&Al[BUF][c0 * 8] = v0;                                           \
    *(bf16x8*)&Al[BUF][c1 * 8] = v1;                                           \
  }

  STAGE_A(0, 0);
  gload16(Wb + (size_t)r0 * DIN + o0, &Bl[0][c0 * 8]);
  gload16(Wb + (size_t)r1 * DIN + o1, &Bl[0][c1 * 8]);
  __syncthreads();

#pragma unroll
  for (int kk = 0; kk < 16; kk++) {
    const int cur = kk & 1, nxt = cur ^ 1;
    if (kk < 15) {
      const int k1 = (kk + 1) * 32;
      STAGE_A(k1, nxt);
      gload16(Wb + (size_t)r0 * DIN + k1 + o0, &Bl[nxt][c0 * 8]);
      gload16(Wb + (size_t)r1 * DIN + k1 + o1, &Bl[nxt][c1 * 8]);
    }
    bf16x8 af[4], bfr[4];
#pragma unroll
    for (int i = 0; i < 4; i++)
      af[i] = *(const bf16x8*)&Al[cur][(wm + i * 16 + ln) * 32 + quad * 8];
#pragma unroll
    for (int j = 0; j < 4; j++)
      bfr[j] = *(const bf16x8*)&Bl[cur][(wn + j * 16 + ln) * 32 + quad * 8];
#pragma unroll
    for (int i = 0; i < 4; i++)
#pragma unroll
      for (int j = 0; j < 4; j++)
        acc[i][j] = __builtin_amdgcn_mfma_f32_16x16x32_bf16(af[i], bfr[j], acc[i][j], 0, 0, 0);
    __syncthreads();
  }
#undef STAGE_A

#pragma unroll
  for (int i = 0; i < 4; i++)
#pragma unroll
    for (int j = 0; j < 4; j++)
#pragma unroll
      for (int r = 0; r < 4; r++) {
        const int m = rowBase + wm + i * 16 + quad * 4 + r;
        const int n = colBase + wn + j * 16 + ln;
        outf[(size_t)m * DIN + n] = acc[i][j][r] + bo[n];
      }
}

extern "C" void kernel_launch(void* const* d_in, const int* in_sizes, int n_in,
                              void* d_out, int out_size, void* d_ws, size_t ws_size,
                              hipStream_t stream) {
  const float* x    = (const float*)d_in[0];
  const float* ctx  = (const float*)d_in[1];
  const float* bias = (const float*)d_in[2];
  const float* Wq   = (const float*)d_in[3];
  const float* Wk   = (const float*)d_in[4];
  const float* Wv   = (const float*)d_in[5];
  const float* Wo   = (const float*)d_in[6];
  const float* bo   = (const float*)d_in[7];
  float* out = (float*)d_out;

  char* p = (char*)d_ws;
  bf16* xb   = (bf16*)(p + 0);              // 4 MB
  bf16* cb   = (bf16*)(p + 4194304);        // 8 MB (aliased by op0 after QKV GEMM)
  bf16* wqb  = (bf16*)(p + 12582912);       // 512 KB
  bf16* wkb  = (bf16*)(p + 13107200);
  bf16* wvb  = (bf16*)(p + 13631488);
  bf16* wob  = (bf16*)(p + 14155776);
  bf16* qb   = (bf16*)(p + 14680064);       // 4 MB
  bf16* kb   = (bf16*)(p + 18874368);       // 8 MB
  bf16* vtb  = (bf16*)(p + 27262976);       // 8 MB
  float* op1 = (float*)(p + 35651584);      // 8 MB
  float* lpart = (float*)(p + 44040192);    // 256 KB
  float* op0 = (float*)cb;                  // 8 MB alias: cb dead after gemm_qkv

  cvt_all<<<7168, 256, 0, stream>>>(x, ctx, Wq, Wk, Wv, Wo, xb, cb, wqb, wkb, wvb, wob);
  gemm_qkv<<<dim3(4, 64, 3), 256, 0, stream>>>(xb, cb, wqb, wkb, wvb, qb, kb, vtb);
  attn_fwd<<<dim3(NQ / 32, H, B * KSPLIT), 128, 0, stream>>>(qb, kb, vtb, bias, op0, op1, lpart);
  gemm_out<<<dim3(4, 32), 256, 0, stream>>>(op0, op1, lpart, wob, out, bo);
}

// Round 6
// 196.635 us; speedup vs baseline: 1.0741x; 1.0741x over previous
//
#include <hip/hip_runtime.h>

#define H 8
#define DH 64
#define NQ 1024
#define NK 2048
#define DIN 512
#define B 4
#define KSPLIT 2
#define KRANGE (NK / KSPLIT)   // 1024
#define KTILES (KRANGE / 64)   // 16
#define BHNQ (B * H * NQ)

typedef __bf16 bf16;
typedef __bf16 bf16x8 __attribute__((ext_vector_type(8)));
typedef __bf16 bf16x4 __attribute__((ext_vector_type(4)));
typedef float floatx4 __attribute__((ext_vector_type(4)));

__device__ inline void gload16(const void* g, void* l) {
  __builtin_amdgcn_global_load_lds(
      (const __attribute__((address_space(1))) void*)g,
      (__attribute__((address_space(3))) void*)l, 16, 0, 0);
}

// ---------------- fp32 -> bf16 convert, all six tensors in one launch --------
__global__ void cvt_all(const float* __restrict__ x, const float* __restrict__ ctx,
                        const float* __restrict__ wq, const float* __restrict__ wk,
                        const float* __restrict__ wv, const float* __restrict__ wo,
                        bf16* xb, bf16* cb, bf16* wqb, bf16* wkb, bf16* wvb, bf16* wob) {
  long i = ((long)blockIdx.x * 256 + threadIdx.x) * 4;
  const float* s; bf16* d; long o;
  if (i < 2097152)      { s = x;   d = xb;  o = i; }
  else if (i < 6291456) { s = ctx; d = cb;  o = i - 2097152; }
  else if (i < 6553600) { s = wq;  d = wqb; o = i - 6291456; }
  else if (i < 6815744) { s = wk;  d = wkb; o = i - 6553600; }
  else if (i < 7077888) { s = wv;  d = wvb; o = i - 6815744; }
  else                  { s = wo;  d = wob; o = i - 7077888; }
  float4 f = *(const float4*)(s + o);
  bf16x4 v = { (bf16)f.x, (bf16)f.y, (bf16)f.z, (bf16)f.w };
  *(bf16x4*)(d + o) = v;
}

// ---------------- fused Q/K/V projection GEMM (C = A @ W^T) ------------------
// 64x128 tiles (M-split for latency overlap), grid (4, 128, 3), 24 KB LDS.
// z: 0 -> Q (scale 0.125, [b,h,tok,d]), 1 -> K ([b,h,tok,d]), 2 -> V^T.
// V^T uses operand-swapped MFMA so stores are token-contiguous (no 2B scatter).
__global__ __launch_bounds__(256) void gemm_qkv(
    const bf16* __restrict__ xb, const bf16* __restrict__ cb,
    const bf16* __restrict__ wqb, const bf16* __restrict__ wkb, const bf16* __restrict__ wvb,
    bf16* __restrict__ qb, bf16* __restrict__ kb, bf16* __restrict__ vtb) {
  const int which = blockIdx.z;
  if (which == 0 && blockIdx.y >= 64) return;
  const bf16* A = (which == 0) ? xb : cb;
  const bf16* W = (which == 0) ? wqb : ((which == 1) ? wkb : wvb);
  bf16* outb = (which == 0) ? qb : ((which == 1) ? kb : vtb);
  const int logT = (which == 0) ? 10 : 11;
  const float scale = (which == 0) ? 0.125f : 1.0f;
  const bool vmode = (which == 2);

  __shared__ bf16 Al[2][64 * 32];   // 4 KB each
  __shared__ bf16 Bl[2][128 * 32];  // 8 KB each
  const int t = threadIdx.x;
  const int lane = t & 63, w = t >> 6;
  const int ln = lane & 15, quad = lane >> 4;
  const int wm = (w >> 1) * 32, wn = (w & 1) * 64;
  const int rowBase = blockIdx.y * 64;
  const int colBase = blockIdx.x * 128;

  floatx4 acc[2][4] = {};
  // A-tile: 64x32, one gload16/thread. B-tile: 128x32, two gload16/thread.
  const int rA = t >> 2, oA = (t & 3) * 8;
  const int c0 = t, c1 = t + 256;
  const int rB0 = c0 >> 2, oB0 = (c0 & 3) * 8;
  const int rB1 = c1 >> 2, oB1 = (c1 & 3) * 8;
  const bf16* Ab = A + (size_t)rowBase * DIN;
  const bf16* Wb = W + (size_t)colBase * DIN;

  gload16(Ab + (size_t)rA * DIN + oA, &Al[0][t * 8]);
  gload16(Wb + (size_t)rB0 * DIN + oB0, &Bl[0][c0 * 8]);
  gload16(Wb + (size_t)rB1 * DIN + oB1, &Bl[0][c1 * 8]);
  __syncthreads();

  for (int k0 = 0; k0 < DIN; k0 += 32) {
    const int cur = (k0 >> 5) & 1, nxt = cur ^ 1;
    if (k0 + 32 < DIN) {
      gload16(Ab + (size_t)rA * DIN + k0 + 32 + oA, &Al[nxt][t * 8]);
      gload16(Wb + (size_t)rB0 * DIN + k0 + 32 + oB0, &Bl[nxt][c0 * 8]);
      gload16(Wb + (size_t)rB1 * DIN + k0 + 32 + oB1, &Bl[nxt][c1 * 8]);
    }
    bf16x8 af[2], bfr[4];
#pragma unroll
    for (int i = 0; i < 2; i++)
      af[i] = *(const bf16x8*)&Al[cur][(wm + i * 16 + ln) * 32 + quad * 8];
#pragma unroll
    for (int j = 0; j < 4; j++)
      bfr[j] = *(const bf16x8*)&Bl[cur][(wn + j * 16 + ln) * 32 + quad * 8];
    if (!vmode) {
#pragma unroll
      for (int i = 0; i < 2; i++)
#pragma unroll
        for (int j = 0; j < 4; j++)
          acc[i][j] = __builtin_amdgcn_mfma_f32_16x16x32_bf16(af[i], bfr[j], acc[i][j], 0, 0, 0);
    } else {
#pragma unroll
      for (int i = 0; i < 2; i++)
#pragma unroll
        for (int j = 0; j < 4; j++)
          acc[i][j] = __builtin_amdgcn_mfma_f32_16x16x32_bf16(bfr[j], af[i], acc[i][j], 0, 0, 0);
    }
    __syncthreads();
  }

  const int T = 1 << logT;
#pragma unroll
  for (int i = 0; i < 2; i++)
#pragma unroll
    for (int j = 0; j < 4; j++)
#pragma unroll
      for (int r = 0; r < 4; r++) {
        if (!vmode) {
          // acc rows = tokens, cols = weight dim
          const int m = rowBase + wm + i * 16 + quad * 4 + r;
          const int n = colBase + wn + j * 16 + ln;
          const float v = acc[i][j][r] * scale;
          const int bb = m >> logT, tok = m & (T - 1);
          const int hh = n >> 6, d = n & 63;
          outb[((((size_t)(bb * H + hh)) << logT) + tok) * DH + d] = (bf16)v;
        } else {
          // swapped: acc rows = weight dim, cols = tokens (ln-contiguous stores)
          const int dg = colBase + wn + j * 16 + quad * 4 + r;
          const int m = rowBase + wm + i * 16 + ln;
          const int bb = m >> logT, tok = m & (T - 1);
          const int hh = dg >> 6, d = dg & 63;
          outb[(((size_t)(bb * H + hh) * DH + d) << logT) + tok] = (bf16)acc[i][j][r];
        }
      }
}

// ---------------- flash attention, static-max softmax, Nk-split --------------
// grid (NQ/64, H, B*KSPLIT), block 128 (2 waves; wave w owns 32 q-rows as two
// 16-row subtiles). Each K/V LDS fragment feeds BOTH subtiles (halves LDS
// reads + DMA per q-row). XOR source-permute swizzle; bias = QK^T acc init;
// l via ones-MFMA.
__global__ __launch_bounds__(128) void attn_fwd(
    const bf16* __restrict__ q, const bf16* __restrict__ k,
    const bf16* __restrict__ vt, const float* __restrict__ bias,
    float* __restrict__ op0, float* __restrict__ op1, float* __restrict__ lpart) {
  __shared__ bf16 KL[64 * 64];        // 8 KB
  __shared__ bf16 VL[64 * 64];        // 8 KB
  __shared__ bf16 Pl[2][2][16 * 64];  // 8 KB (wave, subtile)
  const int tid = threadIdx.x;
  const int lane = tid & 63, w = tid >> 6;
  const int ln = lane & 15, quad = lane >> 4;
  const int hh = blockIdx.y;
  const int b = blockIdx.z >> 1, ks = blockIdx.z & 1;
  const int q0 = blockIdx.x * 64;
  const int k0 = ks * KRANGE;
  const size_t bh = (size_t)b * H + hh;
  const bf16* qp = q + bh * NQ * DH;
  const bf16* kp = k + bh * NK * DH;
  const bf16* vp = vt + bh * DH * NK;
  // bias rows for this wave: q0 + w*32 + s*16 + quad*4 + r, col offset ln
  const float* bp = bias + ((size_t)b * NQ + q0 + w * 32 + quad * 4) * NK + ln;

  bf16x8 qf[2][2];
#pragma unroll
  for (int s = 0; s < 2; s++)
#pragma unroll
    for (int kc = 0; kc < 2; kc++)
      qf[s][kc] = *(const bf16x8*)(qp + (size_t)(q0 + w * 32 + s * 16 + ln) * DH + kc * 32 + quad * 8);

  floatx4 o[2][4] = {};
  floatx4 lac[2] = {};
  const bf16x8 ones = {(bf16)1.f, (bf16)1.f, (bf16)1.f, (bf16)1.f,
                       (bf16)1.f, (bf16)1.f, (bf16)1.f, (bf16)1.f};
  constexpr float L2E = 1.44269504f;
  constexpr float OFF = 34.6246810f;  // 24 * log2(e); scores+bias << 24 always

  for (int tt = 0; tt < KTILES; tt++) {
    const int nk0 = k0 + tt * 64;
    // ---- stage K,V via DMA; bias tile into registers (latency covered by barrier drain)
#pragma unroll
    for (int s = 0; s < 4; s++) {
      const int i = s * 128 + tid;
      const int sr = i >> 3, sc = (i & 7) ^ (sr & 7);
      gload16(kp + (size_t)(nk0 + sr) * DH + sc * 8, &KL[i * 8]);
      gload16(vp + (size_t)sr * NK + nk0 + sc * 8, &VL[i * 8]);
    }
    float bc[2][4][4];
#pragma unroll
    for (int s = 0; s < 2; s++)
#pragma unroll
      for (int j = 0; j < 4; j++)
#pragma unroll
        for (int r = 0; r < 4; r++)
          bc[s][j][r] = bp[(size_t)(s * 16 + r) * NK + nk0 + j * 16];
    __syncthreads();

    // ---- QK^T for both subtiles, sharing each K fragment ----
    floatx4 s4[2][4];
#pragma unroll
    for (int s = 0; s < 2; s++)
#pragma unroll
      for (int j = 0; j < 4; j++) {
        s4[s][j][0] = bc[s][j][0]; s4[s][j][1] = bc[s][j][1];
        s4[s][j][2] = bc[s][j][2]; s4[s][j][3] = bc[s][j][3];
      }
#pragma unroll
    for (int j = 0; j < 4; j++)
#pragma unroll
      for (int kc = 0; kc < 2; kc++) {
        const int kr = j * 16 + ln;
        bf16x8 kf = *(const bf16x8*)&KL[kr * 64 + (((kc * 4 + quad) ^ (kr & 7)) * 8)];
        s4[0][j] = __builtin_amdgcn_mfma_f32_16x16x32_bf16(qf[0][kc], kf, s4[0][j], 0, 0, 0);
        s4[1][j] = __builtin_amdgcn_mfma_f32_16x16x32_bf16(qf[1][kc], kf, s4[1][j], 0, 0, 0);
      }

    // ---- p = exp2(s*L2E - OFF) ----
#pragma unroll
    for (int s = 0; s < 2; s++)
#pragma unroll
      for (int j = 0; j < 4; j++)
#pragma unroll
        for (int r = 0; r < 4; r++)
          s4[s][j][r] = exp2f(fmaf(s4[s][j][r], L2E, -OFF));

    // ---- P: C-layout -> swizzled LDS -> A-layout fragments (both subtiles)
#pragma unroll
    for (int s = 0; s < 2; s++)
#pragma unroll
      for (int j = 0; j < 4; j++)
#pragma unroll
        for (int r = 0; r < 4; r++) {
          const int m = quad * 4 + r;
          Pl[w][s][m * 64 + (((j * 2 + (ln >> 3)) ^ (m & 7)) * 8) + (ln & 7)] = (bf16)s4[s][j][r];
        }
    asm volatile("s_waitcnt lgkmcnt(0)" ::: "memory");
    bf16x8 pf[2][2];
#pragma unroll
    for (int s = 0; s < 2; s++)
#pragma unroll
      for (int kc = 0; kc < 2; kc++)
        pf[s][kc] = *(const bf16x8*)&Pl[w][s][ln * 64 + (((kc * 4 + quad) ^ (ln & 7)) * 8)];

    // ---- l += P @ ones ----
#pragma unroll
    for (int s = 0; s < 2; s++)
#pragma unroll
      for (int kc = 0; kc < 2; kc++)
        lac[s] = __builtin_amdgcn_mfma_f32_16x16x32_bf16(pf[s][kc], ones, lac[s], 0, 0, 0);

    // ---- O += P @ V, sharing each V fragment across subtiles ----
#pragma unroll
    for (int jn = 0; jn < 4; jn++)
#pragma unroll
      for (int kc = 0; kc < 2; kc++) {
        const int vr = jn * 16 + ln;
        bf16x8 vf = *(const bf16x8*)&VL[vr * 64 + (((kc * 4 + quad) ^ (vr & 7)) * 8)];
        o[0][jn] = __builtin_amdgcn_mfma_f32_16x16x32_bf16(pf[0][kc], vf, o[0][jn], 0, 0, 0);
        o[1][jn] = __builtin_amdgcn_mfma_f32_16x16x32_bf16(pf[1][kc], vf, o[1][jn], 0, 0, 0);
      }
    __syncthreads();
  }

#pragma unroll
  for (int s = 0; s < 2; s++) {
    float* op = (ks ? op1 : op0) +
                ((size_t)b * NQ + q0 + w * 32 + s * 16 + quad * 4) * DIN + hh * 64 + ln;
#pragma unroll
    for (int jn = 0; jn < 4; jn++)
#pragma unroll
      for (int r = 0; r < 4; r++)
        op[(size_t)r * DIN + jn * 16] = o[s][jn][r];
    if (ln == 0) {
      float4 lv = {lac[s][0], lac[s][1], lac[s][2], lac[s][3]};
      *(float4*)&lpart[((size_t)ks * B * H + b * H + hh) * NQ + q0 + w * 32 + s * 16 + quad * 4] = lv;
    }
  }
}

// ---------------- final projection fused with K-split combine ----------------
// out = ((op0+op1) * (1/l)) @ Wo^T + bo. 64x128 tiles, grid (4,64) = 256 blocks.
__global__ __launch_bounds__(256) void gemm_out(
    const float* __restrict__ op0, const float* __restrict__ op1,
    const float* __restrict__ lp, const bf16* __restrict__ W,
    float* __restrict__ outf, const float* __restrict__ bo) {
  __shared__ bf16 Al[2][64 * 32];   // 4 KB each
  __shared__ bf16 Bl[2][128 * 32];  // 8 KB each
  const int t = threadIdx.x;
  const int lane = t & 63, w = t >> 6;
  const int ln = lane & 15, quad = lane >> 4;
  const int wm = (w >> 1) * 32, wn = (w & 1) * 64;
  const int rowBase = blockIdx.y * 64;
  const int colBase = blockIdx.x * 128;

  floatx4 acc[2][4] = {};
  const int rA = t >> 2, oA = (t & 3) * 8;
  const int c0 = t, c1 = t + 256;
  const int rB0 = c0 >> 2, oB0 = (c0 & 3) * 8;
  const int rB1 = c1 >> 2, oB1 = (c1 & 3) * 8;
  const int m0 = rowBase + rA;
  const bf16* Wb = W + (size_t)colBase * DIN;

  // per-head 1/l for the staged row (k-loop unrolled -> constant indexing)
  float linv0[8];
#pragma unroll
  for (int h = 0; h < 8; h++) {
    const int i0 = ((m0 >> 10) * H + h) * NQ + (m0 & 1023);
    linv0[h] = 1.0f / (lp[i0] + lp[BHNQ + i0]);
  }

#define STAGE_A(K0V, BUF)                                                      \
  {                                                                            \
    const float sA = linv0[(K0V) >> 6];                                        \
    const float* pa0 = op0 + (size_t)m0 * DIN + (K0V) + oA;                    \
    const float* pa1 = op1 + (size_t)m0 * DIN + (K0V) + oA;                    \
    float4 xa = *(const float4*)pa0, xb2 = *(const float4*)(pa0 + 4);          \
    float4 ya = *(const float4*)pa1, yb = *(const float4*)(pa1 + 4);           \
    bf16x8 v0 = {(bf16)((xa.x + ya.x) * sA), (bf16)((xa.y + ya.y) * sA),       \
                 (bf16)((xa.z + ya.z) * sA), (bf16)((xa.w + ya.w) * sA),       \
                 (bf16)((xb2.x + yb.x) * sA), (bf16)((xb2.y + yb.y) * sA),     \
                 (bf16)((xb2.z + yb.z) * sA), (bf16)((xb2.w + yb.w) * sA)};    \
    *(bf16x8*)&Al[BUF][t * 8] = v0;                                            \
  }

  STAGE_A(0, 0);
  gload16(Wb + (size_t)rB0 * DIN + oB0, &Bl[0][c0 * 8]);
  gload16(Wb + (size_t)rB1 * DIN + oB1, &Bl[0][c1 * 8]);
  __syncthreads();

#pragma unroll
  for (int kk = 0; kk < 16; kk++) {
    const int cur = kk & 1, nxt = cur ^ 1;
    if (kk < 15) {
      const int k1 = (kk + 1) * 32;
      STAGE_A(k1, nxt);
      gload16(Wb + (size_t)rB0 * DIN + k1 + oB0, &Bl[nxt][c0 * 8]);
      gload16(Wb + (size_t)rB1 * DIN + k1 + oB1, &Bl[nxt][c1 * 8]);
    }
    bf16x8 af[2], bfr[4];
#pragma unroll
    for (int i = 0; i < 2; i++)
      af[i] = *(const bf16x8*)&Al[cur][(wm + i * 16 + ln) * 32 + quad * 8];
#pragma unroll
    for (int j = 0; j < 4; j++)
      bfr[j] = *(const bf16x8*)&Bl[cur][(wn + j * 16 + ln) * 32 + quad * 8];
#pragma unroll
    for (int i = 0; i < 2; i++)
#pragma unroll
      for (int j = 0; j < 4; j++)
        acc[i][j] = __builtin_amdgcn_mfma_f32_16x16x32_bf16(af[i], bfr[j], acc[i][j], 0, 0, 0);
    __syncthreads();
  }
#undef STAGE_A

#pragma unroll
  for (int i = 0; i < 2; i++)
#pragma unroll
    for (int j = 0; j < 4; j++)
#pragma unroll
      for (int r = 0; r < 4; r++) {
        const int m = rowBase + wm + i * 16 + quad * 4 + r;
        const int n = colBase + wn + j * 16 + ln;
        outf[(size_t)m * DIN + n] = acc[i][j][r] + bo[n];
      }
}

extern "C" void kernel_launch(void* const* d_in, const int* in_sizes, int n_in,
                              void* d_out, int out_size, void* d_ws, size_t ws_size,
                              hipStream_t stream) {
  const float* x    = (const float*)d_in[0];
  const float* ctx  = (const float*)d_in[1];
  const float* bias = (const float*)d_in[2];
  const float* Wq   = (const float*)d_in[3];
  const float* Wk   = (const float*)d_in[4];
  const float* Wv   = (const float*)d_in[5];
  const float* Wo   = (const float*)d_in[6];
  const float* bo   = (const float*)d_in[7];
  float* out = (float*)d_out;

  char* p = (char*)d_ws;
  bf16* xb   = (bf16*)(p + 0);              // 4 MB
  bf16* cb   = (bf16*)(p + 4194304);        // 8 MB (aliased by op0 after QKV GEMM)
  bf16* wqb  = (bf16*)(p + 12582912);       // 512 KB
  bf16* wkb  = (bf16*)(p + 13107200);
  bf16* wvb  = (bf16*)(p + 13631488);
  bf16* wob  = (bf16*)(p + 14155776);
  bf16* qb   = (bf16*)(p + 14680064);       // 4 MB
  bf16* kb   = (bf16*)(p + 18874368);       // 8 MB
  bf16* vtb  = (bf16*)(p + 27262976);       // 8 MB
  float* op1 = (float*)(p + 35651584);      // 8 MB
  float* lpart = (float*)(p + 44040192);    // 256 KB
  float* op0 = (float*)cb;                  // 8 MB alias: cb dead after gemm_qkv

  cvt_all<<<7168, 256, 0, stream>>>(x, ctx, Wq, Wk, Wv, Wo, xb, cb, wqb, wkb, wvb, wob);
  gemm_qkv<<<dim3(4, 128, 3), 256, 0, stream>>>(xb, cb, wqb, wkb, wvb, qb, kb, vtb);
  attn_fwd<<<dim3(NQ / 64, H, B * KSPLIT), 128, 0, stream>>>(qb, kb, vtb, bias, op0, op1, lpart);
  gemm_out<<<dim3(4, 64), 256, 0, stream>>>(op0, op1, lpart, wob, out, bo);
}